// Round 1
// baseline (5182.644 us; speedup 1.0000x reference)
//
#include <hip/hip_runtime.h>
#include <math.h>

#define NS 16
#define NC 4
#define NH 256
#define BATCH 262144

// One wave (64 lanes) processes 4 batch elements; 4 waves/block -> 16 elems/block.
// Rows owned by lane: r = l + 64*j, j=0..3.

__device__ __forceinline__ float dot4f(float4 a, float4 b) {
    return a.x*b.x + a.y*b.y + a.z*b.z + a.w*b.w;
}
__device__ __forceinline__ float wsum16(float v) {
    v += __shfl_xor(v, 1, 64);
    v += __shfl_xor(v, 2, 64);
    v += __shfl_xor(v, 4, 64);
    v += __shfl_xor(v, 8, 64);
    return v;
}
__device__ __forceinline__ float logsig(float a) {
    return fminf(a, 0.f) - log1pf(expf(-fabsf(a)));
}
__device__ __forceinline__ float siggate(float a) {  // d/da log_sigmoid(a) = sigma(-a)
    return 1.f / (1.f + expf(a));
}

// Transpose a 256x256 row-major matrix: AT[k][r] = A[r][k]
extern "C" __global__ void __launch_bounds__(256)
transpose256(const float* __restrict__ A, float* __restrict__ AT) {
    int k = blockIdx.x;
    int r = threadIdx.x;
    AT[k * NH + r] = A[r * NH + k];
}

template<bool TRANS>
__global__ void __launch_bounds__(256, 2)
comet_fused(const float* __restrict__ Z,
            const float* __restrict__ W1,
            const float* __restrict__ W2f,   // forward W2 (transposed layout if TRANS)
            const float* __restrict__ W3f,   // forward W3 (transposed layout if TRANS)
            const float* __restrict__ W2,    // original row-major (for backward)
            const float* __restrict__ W3,
            const float* __restrict__ W4,
            float* __restrict__ OUT)
{
    __shared__ __align__(16) float h_lds[4][4][NH];       // [wave][e][k]     16 KiB
    __shared__ __align__(16) float m_lds[4][4][NH][NC];   // [wave][e][r][c]  64 KiB

    const int l = threadIdx.x & 63;
    const int w = threadIdx.x >> 6;
    float (*hb)[NH]     = h_lds[w];
    float (*mb)[NH][NC] = m_lds[w];
    const int ebase = (blockIdx.x * 4 + w) * 4;

    float d1g[4][4], d2g[4][4], d3g[4][4];  // [j][e] gate sigma(-a) for row l+64j

    // ---------------- F1: a1 = W1 x ; h1 = ls(a1) ----------------
    {
        float acc[4][4];
        #pragma unroll
        for (int j = 0; j < 4; j++)
            #pragma unroll
            for (int e = 0; e < 4; e++) acc[j][e] = 0.f;
        #pragma unroll
        for (int s4 = 0; s4 < 4; s4++) {
            float4 wf[4];
            #pragma unroll
            for (int j = 0; j < 4; j++)
                wf[j] = *(const float4*)&W1[(l + 64*j) * NS + s4*4];
            #pragma unroll
            for (int e = 0; e < 4; e++) {
                float4 xv = *(const float4*)&Z[(ebase + e) * NS + s4*4];
                #pragma unroll
                for (int j = 0; j < 4; j++) acc[j][e] += dot4f(wf[j], xv);
            }
        }
        #pragma unroll
        for (int j = 0; j < 4; j++)
            #pragma unroll
            for (int e = 0; e < 4; e++) {
                float a = acc[j][e];
                d1g[j][e] = siggate(a);
                hb[e][l + 64*j] = logsig(a);
            }
    }
    __syncthreads();

    // ---------------- F2, F3: a = W h ; h += ls(a) ----------------
#define FWD_LAYER(WPTR, GARR)                                                   \
    {                                                                           \
        float acc[4][4];                                                        \
        _Pragma("unroll")                                                       \
        for (int j = 0; j < 4; j++) {                                           \
            _Pragma("unroll")                                                   \
            for (int e = 0; e < 4; e++) acc[j][e] = 0.f;                        \
        }                                                                       \
        _Pragma("unroll 2")                                                     \
        for (int kk = 0; kk < NH; kk += 4) {                                    \
            float wv[4][4]; /* [k][j] = W[row l+64j][kk+k] */                   \
            if (TRANS) {                                                        \
                _Pragma("unroll")                                               \
                for (int k = 0; k < 4; k++) {                                   \
                    _Pragma("unroll")                                           \
                    for (int j = 0; j < 4; j++)                                 \
                        wv[k][j] = WPTR[(kk + k) * NH + l + 64*j];              \
                }                                                               \
            } else {                                                            \
                _Pragma("unroll")                                               \
                for (int j = 0; j < 4; j++) {                                   \
                    float4 t = *(const float4*)&WPTR[(l + 64*j) * NH + kk];     \
                    wv[0][j] = t.x; wv[1][j] = t.y; wv[2][j] = t.z; wv[3][j] = t.w; \
                }                                                               \
            }                                                                   \
            _Pragma("unroll")                                                   \
            for (int e = 0; e < 4; e++) {                                       \
                float4 hv = *(const float4*)&hb[e][kk];                         \
                _Pragma("unroll")                                               \
                for (int j = 0; j < 4; j++)                                     \
                    acc[j][e] += wv[0][j]*hv.x + wv[1][j]*hv.y                  \
                               + wv[2][j]*hv.z + wv[3][j]*hv.w;                 \
            }                                                                   \
        }                                                                       \
        __syncthreads();                                                        \
        _Pragma("unroll")                                                       \
        for (int j = 0; j < 4; j++) {                                           \
            _Pragma("unroll")                                                   \
            for (int e = 0; e < 4; e++) {                                       \
                float a = acc[j][e];                                            \
                GARR[j][e] = siggate(a);                                        \
                hb[e][l + 64*j] += logsig(a);                                   \
            }                                                                   \
        }                                                                       \
        __syncthreads();                                                        \
    }

    FWD_LAYER(W2f, d2g)
    FWD_LAYER(W3f, d3g)
#undef FWD_LAYER

    // ---------------- F4: dval = W4[s4] . h3  (lane -> (e4, s4)) ----------------
    const int e4 = l >> 4, s4 = l & 15;
    float dval = 0.f;
    {
        #pragma unroll 2
        for (int kk = 0; kk < NH; kk += 4) {
            float4 wf = *(const float4*)&W4[s4 * NH + kk];
            float4 hv = *(const float4*)&hb[e4][kk];
            dval += dot4f(wf, hv);
        }
    }

    // ---------------- B3: g2 = V + W3^T (V .* d3) ----------------
    float gacc[4][4][4];  // [e][c][j], g evaluated at k = l + 64j
    float vf[4][4];       // [c][j] : V_c[l+64j]
    #pragma unroll
    for (int c = 0; c < 4; c++)
        #pragma unroll
        for (int j = 0; j < 4; j++)
            vf[c][j] = W4[(NS + c) * NH + l + 64*j];
    #pragma unroll
    for (int e = 0; e < 4; e++)
        #pragma unroll
        for (int c = 0; c < 4; c++)
            #pragma unroll
            for (int j = 0; j < 4; j++)
                gacc[e][c][j] = vf[c][j];
    // write m3 = V .* d3 for rows owned by this lane
    #pragma unroll
    for (int j = 0; j < 4; j++)
        #pragma unroll
        for (int e = 0; e < 4; e++) {
            float g = d3g[j][e];
            float4 mv = make_float4(vf[0][j]*g, vf[1][j]*g, vf[2][j]*g, vf[3][j]*g);
            *(float4*)&mb[e][l + 64*j][0] = mv;
        }
    __syncthreads();

#define BWD_GEMM(WPTR)                                                          \
    {                                                                           \
        _Pragma("unroll 2")                                                     \
        for (int r = 0; r < NH; r++) {                                          \
            float wc[4];                                                        \
            _Pragma("unroll")                                                   \
            for (int j = 0; j < 4; j++) wc[j] = WPTR[r * NH + l + 64*j];        \
            _Pragma("unroll")                                                   \
            for (int e = 0; e < 4; e++) {                                       \
                float4 mv = *(const float4*)&mb[e][r][0];                       \
                _Pragma("unroll")                                               \
                for (int j = 0; j < 4; j++) {                                   \
                    gacc[e][0][j] += wc[j]*mv.x;                                \
                    gacc[e][1][j] += wc[j]*mv.y;                                \
                    gacc[e][2][j] += wc[j]*mv.z;                                \
                    gacc[e][3][j] += wc[j]*mv.w;                                \
                }                                                               \
            }                                                                   \
        }                                                                       \
    }

    BWD_GEMM(W3)
    __syncthreads();
    // m2 = g2 .* d2
    #pragma unroll
    for (int j = 0; j < 4; j++)
        #pragma unroll
        for (int e = 0; e < 4; e++) {
            float g = d2g[j][e];
            float4 mv = make_float4(gacc[e][0][j]*g, gacc[e][1][j]*g,
                                    gacc[e][2][j]*g, gacc[e][3][j]*g);
            *(float4*)&mb[e][l + 64*j][0] = mv;
        }
    __syncthreads();
    BWD_GEMM(W2)
#undef BWD_GEMM
    __syncthreads();
    // m1 = g1 .* d1
    #pragma unroll
    for (int j = 0; j < 4; j++)
        #pragma unroll
        for (int e = 0; e < 4; e++) {
            float g = d1g[j][e];
            float4 mv = make_float4(gacc[e][0][j]*g, gacc[e][1][j]*g,
                                    gacc[e][2][j]*g, gacc[e][3][j]*g);
            *(float4*)&mb[e][l + 64*j][0] = mv;
        }
    __syncthreads();

    // ---------------- J: jv[e] = sum_r W1[r][s4] * m1[e][r][c4] ----------------
    const int c4 = l >> 4;
    float jv[4] = {0.f, 0.f, 0.f, 0.f};
    #pragma unroll 4
    for (int r = 0; r < NH; r++) {
        float w1v = W1[r * NS + s4];
        #pragma unroll
        for (int e = 0; e < 4; e++) jv[e] += mb[e][r][c4] * w1v;
    }
    __syncthreads();

    // stage J into reused h_lds: jlds[e*64 + c*16 + s]
    float* jlds = (float*)hb;
    #pragma unroll
    for (int e = 0; e < 4; e++) jlds[e * 64 + c4 * 16 + s4] = jv[e];
    __syncthreads();

    // ---------------- MGS projection: out = d - proj_colspace(J^T) d ----------------
    float acol[4];
    acol[0] = jlds[e4 * 64 +      s4];
    acol[1] = jlds[e4 * 64 + 16 + s4];
    acol[2] = jlds[e4 * 64 + 32 + s4];
    acol[3] = jlds[e4 * 64 + 48 + s4];
    #pragma unroll
    for (int c = 0; c < 4; c++) {
        float n2 = wsum16(acol[c] * acol[c]);
        float inv = (n2 > 1e-30f) ? (1.0f / sqrtf(n2)) : 0.0f;
        float q = acol[c] * inv;
        #pragma unroll
        for (int cc = c + 1; cc < 4; cc++) {
            float p = wsum16(acol[cc] * q);
            acol[cc] -= p * q;
        }
        float pd = wsum16(dval * q);
        dval -= pd * q;
    }
    OUT[ebase * NS + l] = dval;
}

extern "C" void kernel_launch(void* const* d_in, const int* in_sizes, int n_in,
                              void* d_out, int out_size, void* d_ws, size_t ws_size,
                              hipStream_t stream) {
    const float* Z  = (const float*)d_in[0];
    const float* W1 = (const float*)d_in[1];
    const float* W2 = (const float*)d_in[2];
    const float* W3 = (const float*)d_in[3];
    const float* W4 = (const float*)d_in[4];
    float* OUT = (float*)d_out;

    const size_t need = (size_t)2 * NH * NH * sizeof(float);  // 512 KiB
    dim3 grid(BATCH / 16), block(256);

    if (ws_size >= need) {
        float* W2T = (float*)d_ws;
        float* W3T = W2T + NH * NH;
        hipLaunchKernelGGL(transpose256, dim3(NH), dim3(NH), 0, stream, W2, W2T);
        hipLaunchKernelGGL(transpose256, dim3(NH), dim3(NH), 0, stream, W3, W3T);
        hipLaunchKernelGGL((comet_fused<true>), grid, block, 0, stream,
                           Z, W1, W2T, W3T, W2, W3, W4, OUT);
    } else {
        hipLaunchKernelGGL((comet_fused<false>), grid, block, 0, stream,
                           Z, W1, W2, W3, W2, W3, W4, OUT);
    }
}

// Round 2
// 2031.514 us; speedup vs baseline: 2.5511x; 2.5511x over previous
//
#include <hip/hip_runtime.h>
#include <math.h>

#define NS 16
#define NC 4
#define NH 256
#define BATCH 262144

typedef _Float16 half8 __attribute__((ext_vector_type(8)));
typedef _Float16 half4v __attribute__((ext_vector_type(4)));
typedef float f32x4 __attribute__((ext_vector_type(4)));

#define MFMA16(a, b, c) __builtin_amdgcn_mfma_f32_16x16x32_f16((a), (b), (c), 0, 0, 0)

// ---------- ws layout (in halves) ----------
#define OFF_W2HI   0
#define OFF_W2LO   65536
#define OFF_W3HI   131072
#define OFF_W3LO   196608
#define OFF_W2THI  262144
#define OFF_W2TLO  327680
#define OFF_W3THI  393216
#define OFF_W3TLO  458752
#define OFF_W1PHI  524288
#define OFF_W1PLO  532480
#define OFF_W1THI  540672
#define OFF_W1TLO  544768
#define OFF_W4HI   548864
#define OFF_W4LO   552960
#define WS_HALVES  557056   // * 2 bytes = 1,114,112

__device__ __forceinline__ float logsigf(float a) {
    return fminf(a, 0.f) - __logf(1.f + __expf(-fabsf(a)));
}
__device__ __forceinline__ float siggf(float a) {   // sigma(-a)
    return 1.f / (1.f + __expf(a));
}
__device__ __forceinline__ void split2(float x, _Float16& h, _Float16& l) {
    h = (_Float16)x;
    l = (_Float16)(x - (float)h);
}
__device__ __forceinline__ float wsum16(float v) {
    v += __shfl_xor(v, 1, 64);
    v += __shfl_xor(v, 2, 64);
    v += __shfl_xor(v, 4, 64);
    v += __shfl_xor(v, 8, 64);
    return v;
}

// ---------------- prep kernels ----------------
extern "C" __global__ void __launch_bounds__(256)
prep_big(const float* __restrict__ W2, const float* __restrict__ W3,
         _Float16* __restrict__ ws) {
    const int mat = blockIdx.y;
    const float* W = mat ? W3 : W2;
    _Float16* Whi  = ws + (mat ? OFF_W3HI  : OFF_W2HI);
    _Float16* Wlo  = Whi + 65536;
    _Float16* WThi = ws + (mat ? OFF_W3THI : OFF_W2THI);
    _Float16* WTlo = WThi + 65536;
    const int r = blockIdx.x, c = threadIdx.x;
    float x = W[r * NH + c];
    _Float16 h, l; split2(x, h, l);
    Whi[r * NH + c] = h;  Wlo[r * NH + c] = l;
    WThi[c * NH + r] = h; WTlo[c * NH + r] = l;
}

extern "C" __global__ void __launch_bounds__(256)
prep_small(const float* __restrict__ W1, const float* __restrict__ W4,
           _Float16* __restrict__ ws) {
    _Float16* W1phi = ws + OFF_W1PHI;
    _Float16* W1plo = ws + OFF_W1PLO;
    _Float16* W1Thi = ws + OFF_W1THI;
    _Float16* W1Tlo = ws + OFF_W1TLO;
    _Float16* W4hi  = ws + OFF_W4HI;
    _Float16* W4lo  = ws + OFF_W4LO;
    const int t = threadIdx.x;   // 0..255 (= W1 row)
    #pragma unroll
    for (int s = 0; s < NS; s++) {
        float x = W1[t * NS + s];
        _Float16 h, l; split2(x, h, l);
        W1phi[t * 32 + s] = h;        W1plo[t * 32 + s] = l;
        W1phi[t * 32 + 16 + s] = (_Float16)0.f;
        W1plo[t * 32 + 16 + s] = (_Float16)0.f;
        W1Thi[s * NH + t] = h;        W1Tlo[s * NH + t] = l;
    }
    #pragma unroll
    for (int q = 0; q < 16; q++) {
        int idx = q * 256 + t;       // covers rows 0..15 of W4
        float x = W4[idx];
        _Float16 h, l; split2(x, h, l);
        W4hi[idx] = h; W4lo[idx] = l;
    }
}

// ---------------- main fused MFMA kernel ----------------
// E=32 elements/block, 512 threads = 8 waves. Wave w owns output rows 32w..32w+31
// (2 M-tiles). Forward N=32 (2 tiles). Backward: 2 passes x 16 elems (N=64, 4 tiles).

#define HSTR 280   // halves; 560 B, 16B-aligned, bank rotation 12 -> ~2-way
#define MSTR 280

__device__ __forceinline__ void gemm_fwd(const _Float16* __restrict__ Ahi,
                                         const _Float16* __restrict__ Alo,
                                         const _Float16* Bh, const _Float16* Bl,
                                         int w, int lo16, int hi4, f32x4 acc[2][2]) {
    #pragma unroll
    for (int ks = 0; ks < 8; ks++) {
        half8 bh[2], bl[2];
        #pragma unroll
        for (int n = 0; n < 2; n++) {
            int off = (16 * n + lo16) * HSTR + ks * 32 + hi4 * 8;
            bh[n] = *(const half8*)&Bh[off];
            bl[n] = *(const half8*)&Bl[off];
        }
        #pragma unroll
        for (int m = 0; m < 2; m++) {
            int woff = (32 * w + 16 * m + lo16) * NH + ks * 32 + hi4 * 8;
            half8 ah = *(const half8*)&Ahi[woff];
            half8 al = *(const half8*)&Alo[woff];
            #pragma unroll
            for (int n = 0; n < 2; n++) {
                acc[m][n] = MFMA16(ah, bh[n], acc[m][n]);
                acc[m][n] = MFMA16(al, bh[n], acc[m][n]);
                acc[m][n] = MFMA16(ah, bl[n], acc[m][n]);
            }
        }
    }
}

__device__ __forceinline__ void gemm_bwd(const _Float16* __restrict__ Ahi,
                                         const _Float16* __restrict__ Alo,
                                         const _Float16* Bh, const _Float16* Bl,
                                         int w, int lo16, int hi4, f32x4 acc[2][4]) {
    #pragma unroll
    for (int ks = 0; ks < 8; ks++) {
        half8 bh[4], bl[4];
        #pragma unroll
        for (int n = 0; n < 4; n++) {
            int off = (16 * n + lo16) * MSTR + ks * 32 + hi4 * 8;
            bh[n] = *(const half8*)&Bh[off];
            bl[n] = *(const half8*)&Bl[off];
        }
        #pragma unroll
        for (int m = 0; m < 2; m++) {
            int woff = (32 * w + 16 * m + lo16) * NH + ks * 32 + hi4 * 8;
            half8 ah = *(const half8*)&Ahi[woff];
            half8 al = *(const half8*)&Alo[woff];
            #pragma unroll
            for (int n = 0; n < 4; n++) {
                acc[m][n] = MFMA16(ah, bh[n], acc[m][n]);
                acc[m][n] = MFMA16(al, bh[n], acc[m][n]);
                acc[m][n] = MFMA16(ah, bl[n], acc[m][n]);
            }
        }
    }
}

__global__ void __launch_bounds__(512, 2)
comet_mfma(const float* __restrict__ Z,
           const float* __restrict__ W4,
           const _Float16* __restrict__ ws,
           float* __restrict__ OUT)
{
    const _Float16* W2hi  = ws + OFF_W2HI;
    const _Float16* W2lo  = ws + OFF_W2LO;
    const _Float16* W3hi  = ws + OFF_W3HI;
    const _Float16* W3lo  = ws + OFF_W3LO;
    const _Float16* W2Thi = ws + OFF_W2THI;
    const _Float16* W2Tlo = ws + OFF_W2TLO;
    const _Float16* W3Thi = ws + OFF_W3THI;
    const _Float16* W3Tlo = ws + OFF_W3TLO;
    const _Float16* W1phi = ws + OFF_W1PHI;
    const _Float16* W1plo = ws + OFF_W1PLO;
    const _Float16* W1Thi = ws + OFF_W1THI;
    const _Float16* W1Tlo = ws + OFF_W1TLO;
    const _Float16* W4hi  = ws + OFF_W4HI;
    const _Float16* W4lo  = ws + OFF_W4LO;

    __shared__ __align__(16) _Float16 Hh[32 * HSTR];   // 17,920 B
    __shared__ __align__(16) _Float16 Hl[32 * HSTR];
    __shared__ __align__(16) _Float16 Mh[64 * MSTR];   // 35,840 B
    __shared__ __align__(16) _Float16 Ml[64 * MSTR];
    __shared__ __align__(16) _Float16 Zh[32 * 32];
    __shared__ __align__(16) _Float16 Zl[32 * 32];
    __shared__ __align__(16) float Vb[4 * 260];
    __shared__ __align__(16) float Pb[8 * 272];        // [w][row16][17]
    __shared__ __align__(16) float Jpart[2 * 16 * 68]; // [kh][s][68]
    __shared__ __align__(16) float Jfin[16 * 132];     // [s][128+pad]

    const int tid  = threadIdx.x;
    const int l    = tid & 63, w = tid >> 6;
    const int lo16 = l & 15, hi4 = l >> 4;
    const int ebase = blockIdx.x * 32;

    // ---- stage Z (k-padded) and V ----
    {
        int e = tid >> 4, s = tid & 15;
        float x = Z[(ebase + e) * NS + s];
        _Float16 h, lo; split2(x, h, lo);
        Zh[e * 32 + s] = h;  Zl[e * 32 + s] = lo;
        Zh[e * 32 + 16 + s] = (_Float16)0.f;
        Zl[e * 32 + 16 + s] = (_Float16)0.f;
        for (int i = tid; i < 1024; i += 512) {
            int c = i >> 8, k = i & 255;
            Vb[c * 260 + k] = W4[(NS + c) * NH + k];
        }
    }
    __syncthreads();

    float g1[2][2][4], g2f[2][2][4], g3f[2][2][4];   // [m][n_f][r]

    // ---- F1 : a1 = W1p @ Zpad ----
    {
        f32x4 acc[2][2];
        #pragma unroll
        for (int m = 0; m < 2; m++)
            #pragma unroll
            for (int n = 0; n < 2; n++) acc[m][n] = (f32x4)(0.f);
        half8 bh[2], bl[2];
        #pragma unroll
        for (int n = 0; n < 2; n++) {
            int off = (16 * n + lo16) * 32 + hi4 * 8;
            bh[n] = *(const half8*)&Zh[off];
            bl[n] = *(const half8*)&Zl[off];
        }
        #pragma unroll
        for (int m = 0; m < 2; m++) {
            int woff = (32 * w + 16 * m + lo16) * 32 + hi4 * 8;
            half8 ah = *(const half8*)&W1phi[woff];
            half8 al = *(const half8*)&W1plo[woff];
            #pragma unroll
            for (int n = 0; n < 2; n++) {
                acc[m][n] = MFMA16(ah, bh[n], acc[m][n]);
                acc[m][n] = MFMA16(al, bh[n], acc[m][n]);
                acc[m][n] = MFMA16(ah, bl[n], acc[m][n]);
            }
        }
        // h1 = ls(a1)   (init write)
        #pragma unroll
        for (int m = 0; m < 2; m++)
            #pragma unroll
            for (int n = 0; n < 2; n++) {
                int hoff = (16 * n + lo16) * HSTR + 32 * w + 16 * m + 4 * hi4;
                half4v nh, nl;
                #pragma unroll
                for (int r = 0; r < 4; r++) {
                    float a = acc[m][n][r];
                    g1[m][n][r] = siggf(a);
                    float hv = logsigf(a);
                    _Float16 xh, xl; split2(hv, xh, xl);
                    nh[r] = xh; nl[r] = xl;
                }
                *(half4v*)&Hh[hoff] = nh;
                *(half4v*)&Hl[hoff] = nl;
            }
    }
    __syncthreads();

    // ---- F2, F3 ----
    #pragma unroll
    for (int L = 0; L < 2; L++) {
        f32x4 acc[2][2];
        #pragma unroll
        for (int m = 0; m < 2; m++)
            #pragma unroll
            for (int n = 0; n < 2; n++) acc[m][n] = (f32x4)(0.f);
        gemm_fwd(L ? W3hi : W2hi, L ? W3lo : W2lo, Hh, Hl, w, lo16, hi4, acc);
        __syncthreads();   // all reads of H done before update
        #pragma unroll
        for (int m = 0; m < 2; m++)
            #pragma unroll
            for (int n = 0; n < 2; n++) {
                int hoff = (16 * n + lo16) * HSTR + 32 * w + 16 * m + 4 * hi4;
                half4v oh = *(const half4v*)&Hh[hoff];
                half4v ol = *(const half4v*)&Hl[hoff];
                half4v nh, nl;
                #pragma unroll
                for (int r = 0; r < 4; r++) {
                    float a = acc[m][n][r];
                    float g = siggf(a);
                    if (L) g3f[m][n][r] = g; else g2f[m][n][r] = g;
                    float hv = (float)oh[r] + (float)ol[r] + logsigf(a);
                    _Float16 xh, xl; split2(hv, xh, xl);
                    nh[r] = xh; nl[r] = xl;
                }
                *(half4v*)&Hh[hoff] = nh;
                *(half4v*)&Hl[hoff] = nl;
            }
        __syncthreads();
    }

    // ---- F4 : d = W4[0:16] @ h3, K split across waves ----
    {
        const int n4 = w & 1, kq = w >> 1;
        f32x4 acc = (f32x4)(0.f);
        #pragma unroll
        for (int i = 0; i < 2; i++) {
            int ks = 2 * kq + i;
            int boff = (16 * n4 + lo16) * HSTR + ks * 32 + hi4 * 8;
            half8 bh = *(const half8*)&Hh[boff];
            half8 bl = *(const half8*)&Hl[boff];
            int woff = lo16 * NH + ks * 32 + hi4 * 8;
            half8 ah = *(const half8*)&W4hi[woff];
            half8 al = *(const half8*)&W4lo[woff];
            acc = MFMA16(ah, bh, acc);
            acc = MFMA16(al, bh, acc);
            acc = MFMA16(ah, bl, acc);
        }
        #pragma unroll
        for (int r = 0; r < 4; r++)
            Pb[w * 272 + (hi4 * 4 + r) * 17 + lo16] = acc[r];
    }

    // ---- backward: 2 passes x 16 elements ----
    #pragma unroll
    for (int p = 0; p < 2; p++) {
        __syncthreads();
        // m3 = V .* d3
        #pragma unroll
        for (int m = 0; m < 2; m++)
            #pragma unroll
            for (int n = 0; n < 4; n++) {
                const int src = (l & 48) | (4 * n + (lo16 >> 2));
                const int c = lo16 & 3;
                const int kbase = 32 * w + 16 * m + 4 * hi4;
                half4v vh, vl;
                #pragma unroll
                for (int r = 0; r < 4; r++) {
                    float g = __shfl(g3f[m][p][r], src, 64);
                    float val = Vb[c * 260 + kbase + r] * g;
                    _Float16 xh, xl; split2(val, xh, xl);
                    vh[r] = xh; vl[r] = xl;
                }
                int moff = (16 * n + lo16) * MSTR + kbase;
                *(half4v*)&Mh[moff] = vh;
                *(half4v*)&Ml[moff] = vl;
            }
        __syncthreads();

        // B3: G2 = W3^T @ m3
        f32x4 acc2[2][4];
        #pragma unroll
        for (int m = 0; m < 2; m++)
            #pragma unroll
            for (int n = 0; n < 4; n++) acc2[m][n] = (f32x4)(0.f);
        gemm_bwd(W3Thi, W3Tlo, Mh, Ml, w, lo16, hi4, acc2);
        __syncthreads();   // readers of m3 done

        // g2 = V + G2 ; m2 = g2 .* d2 ; keep g2 in acc2
        #pragma unroll
        for (int m = 0; m < 2; m++)
            #pragma unroll
            for (int n = 0; n < 4; n++) {
                const int src = (l & 48) | (4 * n + (lo16 >> 2));
                const int c = lo16 & 3;
                const int kbase = 32 * w + 16 * m + 4 * hi4;
                half4v vh, vl;
                #pragma unroll
                for (int r = 0; r < 4; r++) {
                    float gg2 = Vb[c * 260 + kbase + r] + acc2[m][n][r];
                    acc2[m][n][r] = gg2;
                    float g = __shfl(g2f[m][p][r], src, 64);
                    _Float16 xh, xl; split2(gg2 * g, xh, xl);
                    vh[r] = xh; vl[r] = xl;
                }
                int moff = (16 * n + lo16) * MSTR + kbase;
                *(half4v*)&Mh[moff] = vh;
                *(half4v*)&Ml[moff] = vl;
            }
        __syncthreads();

        // B2: g1tot = g2 + W2^T @ m2   (accumulate onto acc2)
        gemm_bwd(W2Thi, W2Tlo, Mh, Ml, w, lo16, hi4, acc2);
        __syncthreads();

        // m1 = g1tot .* d1
        #pragma unroll
        for (int m = 0; m < 2; m++)
            #pragma unroll
            for (int n = 0; n < 4; n++) {
                const int src = (l & 48) | (4 * n + (lo16 >> 2));
                const int kbase = 32 * w + 16 * m + 4 * hi4;
                half4v vh, vl;
                #pragma unroll
                for (int r = 0; r < 4; r++) {
                    float g = __shfl(g1[m][p][r], src, 64);
                    _Float16 xh, xl; split2(acc2[m][n][r] * g, xh, xl);
                    vh[r] = xh; vl[r] = xl;
                }
                int moff = (16 * n + lo16) * MSTR + kbase;
                *(half4v*)&Mh[moff] = vh;
                *(half4v*)&Ml[moff] = vl;
            }
        __syncthreads();

        // J pass: J[s][cols] = W1^T @ m1 ; wave -> (n, k-half)
        {
            const int nj = w & 3, kh = w >> 2;
            f32x4 accj = (f32x4)(0.f);
            #pragma unroll
            for (int i = 0; i < 4; i++) {
                int ks = 4 * kh + i;
                int boff = (16 * nj + lo16) * MSTR + ks * 32 + hi4 * 8;
                half8 bh = *(const half8*)&Mh[boff];
                half8 bl = *(const half8*)&Ml[boff];
                int woff = lo16 * NH + ks * 32 + hi4 * 8;
                half8 ah = *(const half8*)&W1Thi[woff];
                half8 al = *(const half8*)&W1Tlo[woff];
                accj = MFMA16(ah, bh, accj);
                accj = MFMA16(al, bh, accj);
                accj = MFMA16(ah, bl, accj);
            }
            #pragma unroll
            for (int r = 0; r < 4; r++)
                Jpart[kh * 1088 + (hi4 * 4 + r) * 68 + 16 * nj + lo16] = accj[r];
        }
        __syncthreads();
        // reduce k-halves into Jfin
        for (int i = tid; i < 1024; i += 512) {
            int s = i >> 6, c = i & 63;
            Jfin[s * 132 + 64 * p + c] = Jpart[s * 68 + c] + Jpart[1088 + s * 68 + c];
        }
    }
    __syncthreads();

    // ---- projection: each wave handles 4 elements; lane group of 16 per element ----
    {
        const int e = 4 * w + hi4, s = lo16;
        float acol[4];
        #pragma unroll
        for (int c = 0; c < 4; c++) acol[c] = Jfin[s * 132 + 4 * e + c];
        const int n4 = e >> 4, c16 = e & 15;
        float dval = 0.f;
        #pragma unroll
        for (int kq = 0; kq < 4; kq++)
            dval += Pb[(2 * kq + n4) * 272 + s * 17 + c16];
        #pragma unroll
        for (int c = 0; c < 4; c++) {
            float n2 = wsum16(acol[c] * acol[c]);
            float inv = (n2 > 1e-30f) ? (1.0f / sqrtf(n2)) : 0.0f;
            float q = acol[c] * inv;
            #pragma unroll
            for (int cc = c + 1; cc < 4; cc++) {
                float pj = wsum16(acol[cc] * q);
                acol[cc] -= pj * q;
            }
            float pd = wsum16(dval * q);
            dval -= pd * q;
        }
        OUT[(ebase + e) * NS + s] = dval;
    }
}

// ---------------- f32 fallback (round-1 kernel, non-transposed path) ----------------
__device__ __forceinline__ float dot4f(float4 a, float4 b) {
    return a.x*b.x + a.y*b.y + a.z*b.z + a.w*b.w;
}

__global__ void __launch_bounds__(256, 2)
comet_fused_f32(const float* __restrict__ Z,
                const float* __restrict__ W1,
                const float* __restrict__ W2,
                const float* __restrict__ W3,
                const float* __restrict__ W4,
                float* __restrict__ OUT)
{
    __shared__ __align__(16) float h_lds[4][4][NH];
    __shared__ __align__(16) float m_lds[4][4][NH][NC];

    const int l = threadIdx.x & 63;
    const int w = threadIdx.x >> 6;
    float (*hb)[NH]     = h_lds[w];
    float (*mb)[NH][NC] = m_lds[w];
    const int ebase = (blockIdx.x * 4 + w) * 4;

    float d1g[4][4], d2g[4][4], d3g[4][4];

    {
        float acc[4][4];
        #pragma unroll
        for (int j = 0; j < 4; j++)
            #pragma unroll
            for (int e = 0; e < 4; e++) acc[j][e] = 0.f;
        #pragma unroll
        for (int s4 = 0; s4 < 4; s4++) {
            float4 wf[4];
            #pragma unroll
            for (int j = 0; j < 4; j++)
                wf[j] = *(const float4*)&W1[(l + 64*j) * NS + s4*4];
            #pragma unroll
            for (int e = 0; e < 4; e++) {
                float4 xv = *(const float4*)&Z[(ebase + e) * NS + s4*4];
                #pragma unroll
                for (int j = 0; j < 4; j++) acc[j][e] += dot4f(wf[j], xv);
            }
        }
        #pragma unroll
        for (int j = 0; j < 4; j++)
            #pragma unroll
            for (int e = 0; e < 4; e++) {
                float a = acc[j][e];
                d1g[j][e] = siggf(a);
                hb[e][l + 64*j] = logsigf(a);
            }
    }
    __syncthreads();

#define FWD_LAYER(WPTR, GARR)                                                   \
    {                                                                           \
        float acc[4][4];                                                        \
        _Pragma("unroll")                                                       \
        for (int j = 0; j < 4; j++) {                                           \
            _Pragma("unroll")                                                   \
            for (int e = 0; e < 4; e++) acc[j][e] = 0.f;                        \
        }                                                                       \
        _Pragma("unroll 2")                                                     \
        for (int kk = 0; kk < NH; kk += 4) {                                    \
            float wv[4][4];                                                     \
            _Pragma("unroll")                                                   \
            for (int j = 0; j < 4; j++) {                                       \
                float4 t = *(const float4*)&WPTR[(l + 64*j) * NH + kk];         \
                wv[0][j] = t.x; wv[1][j] = t.y; wv[2][j] = t.z; wv[3][j] = t.w; \
            }                                                                   \
            _Pragma("unroll")                                                   \
            for (int e = 0; e < 4; e++) {                                       \
                float4 hv = *(const float4*)&hb[e][kk];                         \
                _Pragma("unroll")                                               \
                for (int j = 0; j < 4; j++)                                     \
                    acc[j][e] += wv[0][j]*hv.x + wv[1][j]*hv.y                  \
                               + wv[2][j]*hv.z + wv[3][j]*hv.w;                 \
            }                                                                   \
        }                                                                       \
        __syncthreads();                                                        \
        _Pragma("unroll")                                                       \
        for (int j = 0; j < 4; j++) {                                           \
            _Pragma("unroll")                                                   \
            for (int e = 0; e < 4; e++) {                                       \
                float a = acc[j][e];                                            \
                GARR[j][e] = siggf(a);                                          \
                hb[e][l + 64*j] += logsigf(a);                                  \
            }                                                                   \
        }                                                                       \
        __syncthreads();                                                        \
    }

    FWD_LAYER(W2, d2g)
    FWD_LAYER(W3, d3g)
#undef FWD_LAYER

    const int e4 = l >> 4, s4 = l & 15;
    float dval = 0.f;
    {
        #pragma unroll 2
        for (int kk = 0; kk < NH; kk += 4) {
            float4 wf = *(const float4*)&W4[s4 * NH + kk];
            float4 hv = *(const float4*)&hb[e4][kk];
            dval += dot4f(wf, hv);
        }
    }

    float gacc[4][4][4];
    float vf[4][4];
    #pragma unroll
    for (int c = 0; c < 4; c++)
        #pragma unroll
        for (int j = 0; j < 4; j++)
            vf[c][j] = W4[(NS + c) * NH + l + 64*j];
    #pragma unroll
    for (int e = 0; e < 4; e++)
        #pragma unroll
        for (int c = 0; c < 4; c++)
            #pragma unroll
            for (int j = 0; j < 4; j++)
                gacc[e][c][j] = vf[c][j];
    #pragma unroll
    for (int j = 0; j < 4; j++)
        #pragma unroll
        for (int e = 0; e < 4; e++) {
            float g = d3g[j][e];
            float4 mv = make_float4(vf[0][j]*g, vf[1][j]*g, vf[2][j]*g, vf[3][j]*g);
            *(float4*)&mb[e][l + 64*j][0] = mv;
        }
    __syncthreads();

#define BWD_GEMM(WPTR)                                                          \
    {                                                                           \
        _Pragma("unroll 2")                                                     \
        for (int r = 0; r < NH; r++) {                                          \
            float wc[4];                                                        \
            _Pragma("unroll")                                                   \
            for (int j = 0; j < 4; j++) wc[j] = WPTR[r * NH + l + 64*j];        \
            _Pragma("unroll")                                                   \
            for (int e = 0; e < 4; e++) {                                       \
                float4 mv = *(const float4*)&mb[e][r][0];                       \
                _Pragma("unroll")                                               \
                for (int j = 0; j < 4; j++) {                                   \
                    gacc[e][0][j] += wc[j]*mv.x;                                \
                    gacc[e][1][j] += wc[j]*mv.y;                                \
                    gacc[e][2][j] += wc[j]*mv.z;                                \
                    gacc[e][3][j] += wc[j]*mv.w;                                \
                }                                                               \
            }                                                                   \
        }                                                                       \
    }

    BWD_GEMM(W3)
    __syncthreads();
    #pragma unroll
    for (int j = 0; j < 4; j++)
        #pragma unroll
        for (int e = 0; e < 4; e++) {
            float g = d2g[j][e];
            float4 mv = make_float4(gacc[e][0][j]*g, gacc[e][1][j]*g,
                                    gacc[e][2][j]*g, gacc[e][3][j]*g);
            *(float4*)&mb[e][l + 64*j][0] = mv;
        }
    __syncthreads();
    BWD_GEMM(W2)
#undef BWD_GEMM
    __syncthreads();
    #pragma unroll
    for (int j = 0; j < 4; j++)
        #pragma unroll
        for (int e = 0; e < 4; e++) {
            float g = d1g[j][e];
            float4 mv = make_float4(gacc[e][0][j]*g, gacc[e][1][j]*g,
                                    gacc[e][2][j]*g, gacc[e][3][j]*g);
            *(float4*)&mb[e][l + 64*j][0] = mv;
        }
    __syncthreads();

    const int c4 = l >> 4;
    float jv[4] = {0.f, 0.f, 0.f, 0.f};
    #pragma unroll 4
    for (int r = 0; r < NH; r++) {
        float w1v = W1[r * NS + s4];
        #pragma unroll
        for (int e = 0; e < 4; e++) jv[e] += mb[e][r][c4] * w1v;
    }
    __syncthreads();

    float* jlds = (float*)hb;
    #pragma unroll
    for (int e = 0; e < 4; e++) jlds[e * 64 + c4 * 16 + s4] = jv[e];
    __syncthreads();

    float acol[4];
    acol[0] = jlds[e4 * 64 +      s4];
    acol[1] = jlds[e4 * 64 + 16 + s4];
    acol[2] = jlds[e4 * 64 + 32 + s4];
    acol[3] = jlds[e4 * 64 + 48 + s4];
    #pragma unroll
    for (int c = 0; c < 4; c++) {
        float n2 = wsum16(acol[c] * acol[c]);
        float inv = (n2 > 1e-30f) ? (1.0f / sqrtf(n2)) : 0.0f;
        float q = acol[c] * inv;
        #pragma unroll
        for (int cc = c + 1; cc < 4; cc++) {
            float p = wsum16(acol[cc] * q);
            acol[cc] -= p * q;
        }
        float pd = wsum16(dval * q);
        dval -= pd * q;
    }
    OUT[ebase * NS + l] = dval;
}

extern "C" void kernel_launch(void* const* d_in, const int* in_sizes, int n_in,
                              void* d_out, int out_size, void* d_ws, size_t ws_size,
                              hipStream_t stream) {
    const float* Z  = (const float*)d_in[0];
    const float* W1 = (const float*)d_in[1];
    const float* W2 = (const float*)d_in[2];
    const float* W3 = (const float*)d_in[3];
    const float* W4 = (const float*)d_in[4];
    float* OUT = (float*)d_out;

    const size_t need = (size_t)WS_HALVES * sizeof(_Float16);

    if (ws_size >= need) {
        _Float16* ws = (_Float16*)d_ws;
        hipLaunchKernelGGL(prep_big, dim3(NH, 2), dim3(NH), 0, stream, W2, W3, ws);
        hipLaunchKernelGGL(prep_small, dim3(1), dim3(NH), 0, stream, W1, W4, ws);
        hipLaunchKernelGGL(comet_mfma, dim3(BATCH / 32), dim3(512), 0, stream,
                           Z, W4, ws, OUT);
    } else {
        hipLaunchKernelGGL(comet_fused_f32, dim3(BATCH / 16), dim3(256), 0, stream,
                           Z, W1, W2, W3, W4, OUT);
    }
}